// Round 16
// baseline (65.181 us; speedup 1.0000x reference)
//
#include <hip/hip_runtime.h>
#include <math.h>

// CTC loss (per-step-normalized fwd/bwd), B=128, C=512, T=512, S=128, L=257.
// Round-16: producer/consumer wave pairing in the scan. Evidence (r13 diag):
// recursion math floor <=62cy/step but composed scan ~220cy/step -- the
// stores/loads/pack overheads serialize into the single wave. Fix: 2 waves
// per chain alternate 8-step group ownership; owner runs ONLY the recursion
// core and hands state (a0..a4, scNext) via LDS + barrier; the off-phase wave
// stores its previous group's rows and gathers its next group's p columns.
// Critical path = recursion + handoff only; stores/loads hidden.
// Combine/final: r15 verbatim (exponent/mantissa logs; 79.5->64.8 win).
// Identity (r4-r15): lh_t = sigma_i * D/(S_t*R_i), i = T-1-t.
// bf16 rows; fp64 block accumulation; clamps -> no NaN possible.

#define BB 128
#define CC 512
#define TT 512
#define SS 128
#define LL 257
#define LPADH 260   // bf16 (ushort) elements per row

typedef unsigned int  uint;
typedef unsigned short ushort;

// ---- fp32 DPP helpers (gfx9 controls; validated on gfx950 rounds 3-15) ----
template<int CTRL>
__device__ __forceinline__ float dpp0_f32(float x){
    int v = __builtin_bit_cast(int, x);
    int r = __builtin_amdgcn_update_dpp(0, v, CTRL, 0xF, 0xF, true);
    return __builtin_bit_cast(float, r);
}
__device__ __forceinline__ float shfl_up1_f32(float x){ return dpp0_f32<0x138>(x); }
__device__ __forceinline__ float red8f(float x){
    x += dpp0_f32<0x111>(x);
    x += dpp0_f32<0x112>(x);
    x += dpp0_f32<0x114>(x);
    return x;
}
__device__ __forceinline__ float tail3f(float x){
    x += dpp0_f32<0x118>(x);
    x += dpp0_f32<0x142>(x);
    x += dpp0_f32<0x143>(x);
    return x;
}
__device__ __forceinline__ float full64f(float x){ return tail3f(red8f(x)); }
__device__ __forceinline__ float readlane63_f32(float x){
    int v = __builtin_bit_cast(int, x);
    return __builtin_bit_cast(float, __builtin_amdgcn_readlane(v, 63));
}
__device__ __forceinline__ float pow2if(int e){
    return __builtin_bit_cast(float, (127 + e) << 23);
}
__device__ __forceinline__ uint pk_bf16(float lo, float hi){
    return (__builtin_bit_cast(uint, hi) & 0xFFFF0000u)
         | (__builtin_bit_cast(uint, lo) >> 16);
}
__device__ __forceinline__ float up_lo(uint u){ return __builtin_bit_cast(float, u << 16); }
__device__ __forceinline__ float up_hi(uint u){ return __builtin_bit_cast(float, u & 0xFFFF0000u); }
__device__ __forceinline__ float up_us(ushort u){ return __builtin_bit_cast(float, ((uint)u) << 16); }
template<int CTRL>
__device__ __forceinline__ double dpp0_f64(double x){
    int2 v = __builtin_bit_cast(int2, x);
    int2 r;
    r.x = __builtin_amdgcn_update_dpp(0, v.x, CTRL, 0xF, 0xF, true);
    r.y = __builtin_amdgcn_update_dpp(0, v.y, CTRL, 0xF, 0xF, true);
    return __builtin_bit_cast(double, r);
}
__device__ __forceinline__ double full64d(double x){
    x += dpp0_f64<0x111>(x); x += dpp0_f64<0x112>(x); x += dpp0_f64<0x114>(x);
    x += dpp0_f64<0x118>(x); x += dpp0_f64<0x142>(x); x += dpp0_f64<0x143>(x);
    return x;
}

// ============ 2-wave producer/consumer row-storing scan ============
template<bool REV>
__device__ __forceinline__ void scan_body(
    int b, int wv, int l, const float* __restrict__ P,
    const int* __restrict__ seqg, int blank,
    ushort* __restrict__ W, ushort* __restrict__ W4, int* __restrict__ Eb)
{
    __shared__ float4 st4[64];
    __shared__ float  st1[64];
    __shared__ float  scSh[1];

    const bool is63 = (l == 63);
    const float* Pb = P + (size_t)b * (CC*TT);
    const int* sq = seqg + b*SS;

    int r1, r3; float m1, m3;
    if (!REV) {
        r1 = sq[2*l]; r3 = sq[2*l+1];
        int ip = (l==0) ? 0 : (2*l-1);
        m1 = (l==0) ? 1.f : ((r1 != sq[ip]) ? 1.f : 0.f);
        m3 = (r3 != r1) ? 1.f : 0.f;
    } else {
        r1 = sq[SS-1-2*l]; r3 = sq[SS-2-2*l];
        int ip = (l==0) ? 0 : (SS-2*l);
        m1 = (l==0) ? 1.f : ((r1 != sq[ip]) ? 1.f : 0.f);
        m3 = (r3 != r1) ? 1.f : 0.f;
    }
    const float* pBp = Pb + (size_t)blank*TT;
    const float* p1p = Pb + (size_t)r1*TT;
    const float* p3p = Pb + (size_t)r3*TT;
    int* EbB = Eb + b*64;

    const int tm0=(4*l+769)>>1, tm1=(4*l+770)>>1, tm2=(4*l+771)>>1, tm3=(4*l+772)>>1;

    float a0=0.f,a1=0.f,a2=0.f,a3=0.f,a4=0.f;
    float scNext = 1.f, Sfull = 0.f;
    const float u0i = (l==0) ? 1.f : 0.f;
    float pbB[8], pb1[8], pb3[8];
    uint sbLo[8], sbHi[8]; float s4f[8];

#define LOADPG(gg)                                                          \
  { _Pragma("unroll")                                                       \
    for (int j=0;j<8;++j){                                                  \
      int pc = REV ? (TT-1-((gg)*8+j)) : ((gg)*8+j);                        \
      pbB[j]=pBp[pc]; pb1[j]=p1p[pc]; pb3[j]=p3p[pc];                       \
    } }

#define STEP(g, j, FIRSTF, MASKF)                                           \
  {                                                                         \
    const int i = (g)*8 + (j);                                              \
    float u0,u1,u2,u3,u4;                                                   \
    if (FIRSTF) { u0=u0i; u1=u0i; u2=0.f; u3=0.f; u4=0.f; }                 \
    else {                                                                  \
      float e3u = shfl_up1_f32(a3);                                         \
      u0 = a0 + e3u; u1 = (a1+a0) + m1*e3u; u2 = a2+a1;                     \
      u3 = (a3+a2) + m3*a1; u4 = a4+a3;                                     \
      if (MASKF) {                                                          \
        if (i >= tm0) u0 = 0.f;                                             \
        if (i >= tm1) u1 = 0.f;                                             \
        if (i >= tm2) u2 = 0.f;                                             \
        if (i >= tm3) u3 = 0.f;                                             \
      }                                                                     \
    }                                                                       \
    float pB=pbB[j], pq=pb1[j], pr=pb3[j];                                  \
    if ((j)==0) { pB*=scNext; pq*=scNext; pr*=scNext; }                     \
    float n0=u0*pB, n1=u1*pq, n2=u2*pB, n3=u3*pr, n4=u4*pB;                 \
    sbLo[j]=pk_bf16(n0,n1); sbHi[j]=pk_bf16(n2,n3); s4f[j]=n4;              \
    if ((j)==5) {                                                           \
      float part=(n0+n1)+(n2+n3); if (is63) part+=n4;                       \
      Sfull = full64f(part);                                                \
    }                                                                       \
    if ((j)==7) {                                                           \
      float Su = readlane63_f32(Sfull);                                     \
      int ex = (__builtin_bit_cast(int, Su) >> 23) & 0xFF;                  \
      int e = (ex==0) ? 0 : (ex-127);                                       \
      e = e < -120 ? -120 : (e > 120 ? 120 : e);                            \
      scNext = pow2if(-e);                                                  \
      if (REV && l==0 && (g)+1 < 64) EbB[(g)+1] = e;                        \
    }                                                                       \
    a0=n0; a1=n1; a2=n2; a3=n3; a4=n4;                                      \
  }

#define RGROUP(g, FIRSTF, MASKF)                                            \
    STEP(g,0,FIRSTF,MASKF) STEP(g,1,false,MASKF) STEP(g,2,false,MASKF)      \
    STEP(g,3,false,MASKF)  STEP(g,4,false,MASKF) STEP(g,5,false,MASKF)      \
    STEP(g,6,false,MASKF)  STEP(g,7,false,MASKF)

#define STOREROWS(gg)                                                       \
  {                                                                         \
    ushort* Ww = W + ((size_t)b*TT + (size_t)(gg)*8) * LPADH;               \
    _Pragma("unroll")                                                       \
    for (int j=0;j<8;++j)                                                   \
      *reinterpret_cast<uint2*>(Ww + (size_t)j*LPADH + 4*l)                 \
          = make_uint2(sbLo[j], sbHi[j]);                                   \
    if (is63) {                                                             \
      uint4 pk;                                                             \
      pk.x = pk_bf16(s4f[0], s4f[1]);                                       \
      pk.y = pk_bf16(s4f[2], s4f[3]);                                       \
      pk.z = pk_bf16(s4f[4], s4f[5]);                                       \
      pk.w = pk_bf16(s4f[6], s4f[7]);                                       \
      *reinterpret_cast<uint4*>(W4 + (size_t)b*TT + (size_t)(gg)*8) = pk;   \
    }                                                                       \
  }

    LOADPG(wv)                       // preload my first group's p columns

    for (int g = 0; g < 64; ++g) {
        if ((g & 1) == wv) {
            // ---- owner: recursion core only ----
            if (g > 0) {
                float4 v = st4[l];
                a0 = v.x; a1 = v.y; a2 = v.z; a3 = v.w;
                a4 = st1[l];
                scNext = scSh[0];
            }
            if (g == 0)      { RGROUP(0, true,  false) }
            else if (g < 48) { RGROUP(g, false, false) }
            else             { RGROUP(g, false, true ) }
            st4[l] = make_float4(a0, a1, a2, a3);
            st1[l] = a4;
            if (l == 0) scSh[0] = scNext;
        } else {
            // ---- off-phase: store my previous group, gather my next ----
            if (g >= 1) STOREROWS(g-1)
            if (g >= 1 && g < 63) LOADPG(g+1)
        }
        __syncthreads();
    }
    if (wv == 1) STOREROWS(63)       // last group's rows

#undef STEP
#undef RGROUP
#undef STOREROWS
#undef LOADPG
}

__global__ __launch_bounds__(128, 1)
void ctc_scan(const float* __restrict__ P, const int* __restrict__ seqg,
              const int* __restrict__ blankp, ushort* __restrict__ Wa,
              ushort* __restrict__ Wb, ushort* __restrict__ W4a,
              ushort* __restrict__ W4b, int* __restrict__ Eb)
{
    const int bx = blockIdx.x;
    const int wv = threadIdx.x >> 6, l = threadIdx.x & 63;
    const int blank = blankp[0];
    if (bx < BB) scan_body<false>(bx,      wv, l, P, seqg, blank, Wa, W4a, Eb);
    else         scan_body<true >(bx - BB, wv, l, P, seqg, blank, Wb, W4b, Eb);
}

// ============== combine: r15 verbatim (exponent/mantissa logs) ==============
__global__ __launch_bounds__(64)
void ctc_combine(const ushort* __restrict__ Wa, const ushort* __restrict__ Wb,
                 const ushort* __restrict__ W4a, const ushort* __restrict__ W4b,
                 const int* __restrict__ Eb, const int* __restrict__ seqg,
                 double* __restrict__ Lq)
{
    const int b = blockIdx.x, q = blockIdx.y, l = threadIdx.x;
    const bool is63 = (l == 63);
    const int* sq = seqg + b*SS;
    const int r1 = sq[SS-1-2*l], r3 = sq[SS-2-2*l];
    const int ip = (l==0) ? 0 : (SS-2*l);
    const float m1 = (l==0) ? 1.f : ((r1 != sq[ip]) ? 1.f : 0.f);
    const float m3 = (r3 != r1) ? 1.f : 0.f;
    const int tm0=(4*l+769)>>1, tm1=(4*l+770)>>1, tm2=(4*l+771)>>1, tm3=(4*l+772)>>1;

    const ushort* WaB = Wa + (size_t)b*TT*LPADH;
    const ushort* WbB = Wb + (size_t)b*TT*LPADH;
    const ushort* W4aB = W4a + (size_t)b*TT;
    const ushort* W4bB = W4b + (size_t)b*TT;
    const int t0 = q*8;

    float Rcur;
    {
        const ushort* rw = WbB + (size_t)(TT-1-t0)*LPADH;
        uint2 xu = *reinterpret_cast<const uint2*>(rw + 4*l);
        float rnp = (up_lo(xu.x)+up_hi(xu.x))+(up_lo(xu.y)+up_hi(xu.y));
        if (is63) rnp += up_us(W4bB[TT-1-t0]);
        Rcur = full64f(rnp);
    }

    float PmN = 1.f, PmD = 1.f;
    int   Ei  = 0;

    #pragma unroll
    for (int k=0; k<8; ++k) {
        const int t = t0 + k;
        const int i = TT-1-t;
        const ushort* arow = WaB + (size_t)t*LPADH;
        uint2 au = *reinterpret_cast<const uint2*>(arow + (252 - 4*l));
        float av0 = up_lo(au.x), av1 = up_hi(au.x);
        float av2 = up_lo(au.y), av3 = up_hi(au.y);
        float a256 = up_us(W4aB[t]);
        float ar4 = shfl_up1_f32(av0);
        if (l == 0) ar4 = a256;

        float u0,u1,u2,u3,u4, rnext = 0.f;
        if (i > 0) {
            const ushort* rw = WbB + (size_t)(i-1)*LPADH;
            uint2 bu = *reinterpret_cast<const uint2*>(rw + 4*l);
            float bv0 = up_lo(bu.x), bv1 = up_hi(bu.x);
            float bv2 = up_lo(bu.y), bv3 = up_hi(bu.y);
            float b4 = up_us(W4bB[i-1]);
            float e3u = shfl_up1_f32(bv3);
            u0 = bv0 + e3u;
            u1 = (bv1 + bv0) + m1*e3u;
            u2 = bv2 + bv1;
            u3 = (bv3 + bv2) + m3*bv1;
            u4 = b4 + bv3;
            if (i >= TT - SS) {
                if (i >= tm0) u0 = 0.f;
                if (i >= tm1) u1 = 0.f;
                if (i >= tm2) u2 = 0.f;
                if (i >= tm3) u3 = 0.f;
            }
            rnext = (bv0+bv1)+(bv2+bv3);
            if (is63) rnext += b4;
        } else {
            u0 = (l==0)?1.f:0.f; u1 = u0; u2=0.f; u3=0.f; u4=0.f;
        }
        float trp = ar4*u0 + av3*u1 + av2*u2 + av1*u3;
        if (is63) trp += av0*u4;
        float sap = (av1 + av2) + (av3 + ar4);
        if (is63) sap += av0;

        float D  = full64f(trp);
        float S  = full64f(sap);
        float Rn = full64f(rnext);
        if (is63) {
            float dd = fmaxf(D, 1e-37f);
            uint bn = __builtin_bit_cast(uint, dd);
            Ei += (int)((bn >> 23) & 0xFFu) - 127;
            PmN *= __builtin_bit_cast(float, (bn & 0x807FFFFFu) | (127u<<23));
            float sr = fmaxf(S * Rcur, 1e-37f);
            uint bd = __builtin_bit_cast(uint, sr);
            Ei -= (int)((bd >> 23) & 0xFFu) - 127;
            PmD *= __builtin_bit_cast(float, (bd & 0x807FFFFFu) | (127u<<23));
            if (i > 0 && (i & 7) == 0) Ei -= Eb[b*64 + (i>>3)];
        }
        Rcur = Rn;
    }
    if (is63)
        Lq[b*64 + q] = log((double)PmN / (double)PmD) + (double)Ei * M_LN2;
}

__global__ __launch_bounds__(256)
void ctc_final(const double* __restrict__ Lq, float* __restrict__ out)
{
    const int t = threadIdx.x;
    double v = 0.0;
    #pragma unroll
    for (int k=0;k<32;++k) v += Lq[t + 256*k];
    double s = full64d(v);
    __shared__ double w[4];
    if ((t & 63) == 63) w[t>>6] = s;
    __syncthreads();
    if (t == 0) out[0] = (float)(-(w[0]+w[1]+w[2]+w[3]));
}

extern "C" void kernel_launch(void* const* d_in, const int* in_sizes, int n_in,
                              void* d_out, int out_size, void* d_ws, size_t ws_size,
                              hipStream_t stream)
{
    const float* P     = (const float*)d_in[0];   // params (B,C,T) fp32
    const int*   seq   = (const int*)  d_in[1];   // (B,S) int32
    // d_in[2] = lengths (unused by the reference computation)
    const int*   blank = (const int*)  d_in[3];   // scalar int

    // ws layout (bf16 rows): Wa | Wb (34.1 MB each) | W4a | W4b | Lq | Eb
    ushort* Wa  = (ushort*)d_ws;
    ushort* Wb  = Wa  + (size_t)BB*TT*LPADH;
    ushort* W4a = Wb  + (size_t)BB*TT*LPADH;      // BB*TT ushorts (128 KB)
    ushort* W4b = W4a + (size_t)BB*TT;
    double* Lq  = (double*)(W4b + (size_t)BB*TT); // 8192 doubles
    int*    Eb  = (int*)(Lq + (size_t)BB*64);     // 8192 ints
    (void)ws_size; (void)in_sizes; (void)n_in; (void)out_size;

    ctc_scan<<<2*BB, 128, 0, stream>>>(P, seq, blank, Wa, Wb, W4a, W4b, Eb);
    ctc_combine<<<dim3(BB, 64), 64, 0, stream>>>(Wa, Wb, W4a, W4b, Eb, seq, Lq);
    ctc_final<<<1, 256, 0, stream>>>(Lq, (float*)d_out);
}

// Round 17
// 62.104 us; speedup vs baseline: 1.0496x; 1.0496x over previous
//
#include <hip/hip_runtime.h>
#include <math.h>

// CTC loss (per-step-normalized fwd/bwd), B=128, C=512, T=512, S=128, L=257.
// Round-17: r16 2-wave pairing + (a) float4 off-phase gathers (16 scattered
// dword gathers/group -> 4 float4/group-pair per row: ~4x fewer TA
// line-touches, the per-CU resource that r16 proved is shared between the
// waves) and (b) 16-step slots (32 barriers instead of 64).
// Owner phase: recursion core only (state via LDS). Off phase: store the
// slot it owned previously, gather its next slot's p columns as float4.
// Combine/final: r15 verbatim (exponent/mantissa logs; the r15 win).
// Identity (r4-r15): lh_t = sigma_i * D/(S_t*R_i), i = T-1-t.
// bf16 rows; fp64 block accumulation; clamps -> no NaN possible.

#define BB 128
#define CC 512
#define TT 512
#define SS 128
#define LL 257
#define LPADH 260   // bf16 (ushort) elements per row

typedef unsigned int  uint;
typedef unsigned short ushort;

// ---- fp32 DPP helpers (gfx9 controls; validated on gfx950 rounds 3-16) ----
template<int CTRL>
__device__ __forceinline__ float dpp0_f32(float x){
    int v = __builtin_bit_cast(int, x);
    int r = __builtin_amdgcn_update_dpp(0, v, CTRL, 0xF, 0xF, true);
    return __builtin_bit_cast(float, r);
}
__device__ __forceinline__ float shfl_up1_f32(float x){ return dpp0_f32<0x138>(x); }
__device__ __forceinline__ float red8f(float x){
    x += dpp0_f32<0x111>(x);
    x += dpp0_f32<0x112>(x);
    x += dpp0_f32<0x114>(x);
    return x;
}
__device__ __forceinline__ float tail3f(float x){
    x += dpp0_f32<0x118>(x);
    x += dpp0_f32<0x142>(x);
    x += dpp0_f32<0x143>(x);
    return x;
}
__device__ __forceinline__ float full64f(float x){ return tail3f(red8f(x)); }
__device__ __forceinline__ float readlane63_f32(float x){
    int v = __builtin_bit_cast(int, x);
    return __builtin_bit_cast(float, __builtin_amdgcn_readlane(v, 63));
}
__device__ __forceinline__ float pow2if(int e){
    return __builtin_bit_cast(float, (127 + e) << 23);
}
__device__ __forceinline__ uint pk_bf16(float lo, float hi){
    return (__builtin_bit_cast(uint, hi) & 0xFFFF0000u)
         | (__builtin_bit_cast(uint, lo) >> 16);
}
__device__ __forceinline__ float up_lo(uint u){ return __builtin_bit_cast(float, u << 16); }
__device__ __forceinline__ float up_hi(uint u){ return __builtin_bit_cast(float, u & 0xFFFF0000u); }
__device__ __forceinline__ float up_us(ushort u){ return __builtin_bit_cast(float, ((uint)u) << 16); }
template<int CTRL>
__device__ __forceinline__ double dpp0_f64(double x){
    int2 v = __builtin_bit_cast(int2, x);
    int2 r;
    r.x = __builtin_amdgcn_update_dpp(0, v.x, CTRL, 0xF, 0xF, true);
    r.y = __builtin_amdgcn_update_dpp(0, v.y, CTRL, 0xF, 0xF, true);
    return __builtin_bit_cast(double, r);
}
__device__ __forceinline__ double full64d(double x){
    x += dpp0_f64<0x111>(x); x += dpp0_f64<0x112>(x); x += dpp0_f64<0x114>(x);
    x += dpp0_f64<0x118>(x); x += dpp0_f64<0x142>(x); x += dpp0_f64<0x143>(x);
    return x;
}

// ============ 2-wave producer/consumer scan; 16-step slots; float4 gathers ============
template<bool REV>
__device__ __forceinline__ void scan_body(
    int b, int wv, int l, const float* __restrict__ P,
    const int* __restrict__ seqg, int blank,
    ushort* __restrict__ W, ushort* __restrict__ W4, int* __restrict__ Eb)
{
    __shared__ float4 st4[64];
    __shared__ float  st1[64];
    __shared__ float  scSh[1];

    const bool is63 = (l == 63);
    const float* Pb = P + (size_t)b * (CC*TT);
    const int* sq = seqg + b*SS;

    int r1, r3; float m1, m3;
    if (!REV) {
        r1 = sq[2*l]; r3 = sq[2*l+1];
        int ip = (l==0) ? 0 : (2*l-1);
        m1 = (l==0) ? 1.f : ((r1 != sq[ip]) ? 1.f : 0.f);
        m3 = (r3 != r1) ? 1.f : 0.f;
    } else {
        r1 = sq[SS-1-2*l]; r3 = sq[SS-2-2*l];
        int ip = (l==0) ? 0 : (SS-2*l);
        m1 = (l==0) ? 1.f : ((r1 != sq[ip]) ? 1.f : 0.f);
        m3 = (r3 != r1) ? 1.f : 0.f;
    }
    const float* pBp = Pb + (size_t)blank*TT;
    const float* p1p = Pb + (size_t)r1*TT;
    const float* p3p = Pb + (size_t)r3*TT;
    int* EbB = Eb + b*64;

    const int tm0=(4*l+769)>>1, tm1=(4*l+770)>>1, tm2=(4*l+771)>>1, tm3=(4*l+772)>>1;

    float a0=0.f,a1=0.f,a2=0.f,a3=0.f,a4=0.f;
    float scNext = 1.f, Sfull = 0.f;
    const float u0i = (l==0) ? 1.f : 0.f;
    float4 qB[4], q1[4], q3[4];           // 16 columns (one slot), float4 chunks
    uint sbLo[16], sbHi[16]; float s4f[16];

#define COMP4(v,c) ((c)==0?(v).x:((c)==1?(v).y:((c)==2?(v).z:(v).w)))

// load the 4 float4 column-chunks (per row) covering slot ss (steps 16ss..16ss+15)
#define LOADPG2(ss)                                                         \
  { const int base_ = REV ? (TT - 16*(ss) - 4) : (16*(ss));                 \
    _Pragma("unroll")                                                       \
    for (int k=0;k<4;++k){                                                  \
      int c_ = REV ? (base_ - 4*k) : (base_ + 4*k);                         \
      qB[k] = *reinterpret_cast<const float4*>(pBp + c_);                   \
      q1[k] = *reinterpret_cast<const float4*>(p1p + c_);                   \
      q3[k] = *reinterpret_cast<const float4*>(p3p + c_);                   \
    } }

#define STEP16(ss, j, FIRSTF, MASKF)                                        \
  {                                                                         \
    const int i = 16*(ss) + (j);                                            \
    float u0,u1,u2,u3,u4;                                                   \
    if (FIRSTF) { u0=u0i; u1=u0i; u2=0.f; u3=0.f; u4=0.f; }                 \
    else {                                                                  \
      float e3u = shfl_up1_f32(a3);                                         \
      u0 = a0 + e3u; u1 = (a1+a0) + m1*e3u; u2 = a2+a1;                     \
      u3 = (a3+a2) + m3*a1; u4 = a4+a3;                                     \
      if (MASKF) {                                                          \
        if (i >= tm0) u0 = 0.f;                                             \
        if (i >= tm1) u1 = 0.f;                                             \
        if (i >= tm2) u2 = 0.f;                                             \
        if (i >= tm3) u3 = 0.f;                                             \
      }                                                                     \
    }                                                                       \
    constexpr int ch_ = (j) >> 2;                                           \
    constexpr int cm_ = REV ? ((3-(j)) & 3) : ((j) & 3);                    \
    float pB = COMP4(qB[ch_], cm_);                                         \
    float pq = COMP4(q1[ch_], cm_);                                         \
    float pr = COMP4(q3[ch_], cm_);                                         \
    if (((j)&7)==0) { pB*=scNext; pq*=scNext; pr*=scNext; }                 \
    float n0=u0*pB, n1=u1*pq, n2=u2*pB, n3=u3*pr, n4=u4*pB;                 \
    sbLo[j]=pk_bf16(n0,n1); sbHi[j]=pk_bf16(n2,n3); s4f[j]=n4;              \
    if (((j)&7)==5) {                                                       \
      float part=(n0+n1)+(n2+n3); if (is63) part+=n4;                       \
      Sfull = full64f(part);                                                \
    }                                                                       \
    if (((j)&7)==7) {                                                       \
      float Su = readlane63_f32(Sfull);                                     \
      int ex = (__builtin_bit_cast(int, Su) >> 23) & 0xFF;                  \
      int e = (ex==0) ? 0 : (ex-127);                                       \
      e = e < -120 ? -120 : (e > 120 ? 120 : e);                            \
      scNext = pow2if(-e);                                                  \
      const int g_ = i >> 3;                                                \
      if (REV && l==0 && g_+1 < 64) EbB[g_+1] = e;                          \
    }                                                                       \
    a0=n0; a1=n1; a2=n2; a3=n3; a4=n4;                                      \
  }

#define RG2(ss, FIRSTF, MASKF)                                              \
    STEP16(ss,0,FIRSTF,MASKF) STEP16(ss,1,false,MASKF)                      \
    STEP16(ss,2,false,MASKF)  STEP16(ss,3,false,MASKF)                      \
    STEP16(ss,4,false,MASKF)  STEP16(ss,5,false,MASKF)                      \
    STEP16(ss,6,false,MASKF)  STEP16(ss,7,false,MASKF)                      \
    STEP16(ss,8,false,MASKF)  STEP16(ss,9,false,MASKF)                      \
    STEP16(ss,10,false,MASKF) STEP16(ss,11,false,MASKF)                     \
    STEP16(ss,12,false,MASKF) STEP16(ss,13,false,MASKF)                     \
    STEP16(ss,14,false,MASKF) STEP16(ss,15,false,MASKF)

#define STOREROWS2(ss)                                                      \
  {                                                                         \
    ushort* Ww = W + ((size_t)b*TT + (size_t)(ss)*16) * LPADH;              \
    _Pragma("unroll")                                                       \
    for (int j=0;j<16;++j)                                                  \
      *reinterpret_cast<uint2*>(Ww + (size_t)j*LPADH + 4*l)                 \
          = make_uint2(sbLo[j], sbHi[j]);                                   \
    if (is63) {                                                             \
      uint4 pk0, pk1;                                                       \
      pk0.x = pk_bf16(s4f[0], s4f[1]);   pk0.y = pk_bf16(s4f[2], s4f[3]);   \
      pk0.z = pk_bf16(s4f[4], s4f[5]);   pk0.w = pk_bf16(s4f[6], s4f[7]);   \
      pk1.x = pk_bf16(s4f[8], s4f[9]);   pk1.y = pk_bf16(s4f[10], s4f[11]); \
      pk1.z = pk_bf16(s4f[12], s4f[13]); pk1.w = pk_bf16(s4f[14], s4f[15]); \
      ushort* w4p = W4 + (size_t)b*TT + (size_t)(ss)*16;                    \
      *reinterpret_cast<uint4*>(w4p)     = pk0;                             \
      *reinterpret_cast<uint4*>(w4p + 8) = pk1;                             \
    }                                                                       \
  }

    LOADPG2(wv)                      // preload my first owned slot's columns

    for (int s = 0; s < 32; ++s) {
        if ((s & 1) == wv) {
            // ---- owner: recursion core only ----
            if (s > 0) {
                float4 v = st4[l];
                a0 = v.x; a1 = v.y; a2 = v.z; a3 = v.w;
                a4 = st1[l];
                scNext = scSh[0];
            }
            if (s == 0)      { RG2(0, true,  false) }
            else if (s < 24) { RG2(s, false, false) }
            else             { RG2(s, false, true ) }
            st4[l] = make_float4(a0, a1, a2, a3);
            st1[l] = a4;
            if (l == 0) scSh[0] = scNext;
        } else {
            // ---- off-phase: store my previous slot, gather my next ----
            if (s >= 1) STOREROWS2(s-1)
            if (s >= 1 && s < 31) LOADPG2(s+1)
        }
        __syncthreads();
    }
    if (wv == 1) STOREROWS2(31)      // last slot's rows

#undef STEP16
#undef RG2
#undef STOREROWS2
#undef LOADPG2
#undef COMP4
}

__global__ __launch_bounds__(128, 1)
void ctc_scan(const float* __restrict__ P, const int* __restrict__ seqg,
              const int* __restrict__ blankp, ushort* __restrict__ Wa,
              ushort* __restrict__ Wb, ushort* __restrict__ W4a,
              ushort* __restrict__ W4b, int* __restrict__ Eb)
{
    const int bx = blockIdx.x;
    const int wv = threadIdx.x >> 6, l = threadIdx.x & 63;
    const int blank = blankp[0];
    if (bx < BB) scan_body<false>(bx,      wv, l, P, seqg, blank, Wa, W4a, Eb);
    else         scan_body<true >(bx - BB, wv, l, P, seqg, blank, Wb, W4b, Eb);
}

// ============== combine: r15 verbatim (exponent/mantissa logs) ==============
__global__ __launch_bounds__(64)
void ctc_combine(const ushort* __restrict__ Wa, const ushort* __restrict__ Wb,
                 const ushort* __restrict__ W4a, const ushort* __restrict__ W4b,
                 const int* __restrict__ Eb, const int* __restrict__ seqg,
                 double* __restrict__ Lq)
{
    const int b = blockIdx.x, q = blockIdx.y, l = threadIdx.x;
    const bool is63 = (l == 63);
    const int* sq = seqg + b*SS;
    const int r1 = sq[SS-1-2*l], r3 = sq[SS-2-2*l];
    const int ip = (l==0) ? 0 : (SS-2*l);
    const float m1 = (l==0) ? 1.f : ((r1 != sq[ip]) ? 1.f : 0.f);
    const float m3 = (r3 != r1) ? 1.f : 0.f;
    const int tm0=(4*l+769)>>1, tm1=(4*l+770)>>1, tm2=(4*l+771)>>1, tm3=(4*l+772)>>1;

    const ushort* WaB = Wa + (size_t)b*TT*LPADH;
    const ushort* WbB = Wb + (size_t)b*TT*LPADH;
    const ushort* W4aB = W4a + (size_t)b*TT;
    const ushort* W4bB = W4b + (size_t)b*TT;
    const int t0 = q*8;

    float Rcur;
    {
        const ushort* rw = WbB + (size_t)(TT-1-t0)*LPADH;
        uint2 xu = *reinterpret_cast<const uint2*>(rw + 4*l);
        float rnp = (up_lo(xu.x)+up_hi(xu.x))+(up_lo(xu.y)+up_hi(xu.y));
        if (is63) rnp += up_us(W4bB[TT-1-t0]);
        Rcur = full64f(rnp);
    }

    float PmN = 1.f, PmD = 1.f;
    int   Ei  = 0;

    #pragma unroll
    for (int k=0; k<8; ++k) {
        const int t = t0 + k;
        const int i = TT-1-t;
        const ushort* arow = WaB + (size_t)t*LPADH;
        uint2 au = *reinterpret_cast<const uint2*>(arow + (252 - 4*l));
        float av0 = up_lo(au.x), av1 = up_hi(au.x);
        float av2 = up_lo(au.y), av3 = up_hi(au.y);
        float a256 = up_us(W4aB[t]);
        float ar4 = shfl_up1_f32(av0);
        if (l == 0) ar4 = a256;

        float u0,u1,u2,u3,u4, rnext = 0.f;
        if (i > 0) {
            const ushort* rw = WbB + (size_t)(i-1)*LPADH;
            uint2 bu = *reinterpret_cast<const uint2*>(rw + 4*l);
            float bv0 = up_lo(bu.x), bv1 = up_hi(bu.x);
            float bv2 = up_lo(bu.y), bv3 = up_hi(bu.y);
            float b4 = up_us(W4bB[i-1]);
            float e3u = shfl_up1_f32(bv3);
            u0 = bv0 + e3u;
            u1 = (bv1 + bv0) + m1*e3u;
            u2 = bv2 + bv1;
            u3 = (bv3 + bv2) + m3*bv1;
            u4 = b4 + bv3;
            if (i >= TT - SS) {
                if (i >= tm0) u0 = 0.f;
                if (i >= tm1) u1 = 0.f;
                if (i >= tm2) u2 = 0.f;
                if (i >= tm3) u3 = 0.f;
            }
            rnext = (bv0+bv1)+(bv2+bv3);
            if (is63) rnext += b4;
        } else {
            u0 = (l==0)?1.f:0.f; u1 = u0; u2=0.f; u3=0.f; u4=0.f;
        }
        float trp = ar4*u0 + av3*u1 + av2*u2 + av1*u3;
        if (is63) trp += av0*u4;
        float sap = (av1 + av2) + (av3 + ar4);
        if (is63) sap += av0;

        float D  = full64f(trp);
        float S  = full64f(sap);
        float Rn = full64f(rnext);
        if (is63) {
            float dd = fmaxf(D, 1e-37f);
            uint bn = __builtin_bit_cast(uint, dd);
            Ei += (int)((bn >> 23) & 0xFFu) - 127;
            PmN *= __builtin_bit_cast(float, (bn & 0x807FFFFFu) | (127u<<23));
            float sr = fmaxf(S * Rcur, 1e-37f);
            uint bd = __builtin_bit_cast(uint, sr);
            Ei -= (int)((bd >> 23) & 0xFFu) - 127;
            PmD *= __builtin_bit_cast(float, (bd & 0x807FFFFFu) | (127u<<23));
            if (i > 0 && (i & 7) == 0) Ei -= Eb[b*64 + (i>>3)];
        }
        Rcur = Rn;
    }
    if (is63)
        Lq[b*64 + q] = log((double)PmN / (double)PmD) + (double)Ei * M_LN2;
}

__global__ __launch_bounds__(256)
void ctc_final(const double* __restrict__ Lq, float* __restrict__ out)
{
    const int t = threadIdx.x;
    double v = 0.0;
    #pragma unroll
    for (int k=0;k<32;++k) v += Lq[t + 256*k];
    double s = full64d(v);
    __shared__ double w[4];
    if ((t & 63) == 63) w[t>>6] = s;
    __syncthreads();
    if (t == 0) out[0] = (float)(-(w[0]+w[1]+w[2]+w[3]));
}

extern "C" void kernel_launch(void* const* d_in, const int* in_sizes, int n_in,
                              void* d_out, int out_size, void* d_ws, size_t ws_size,
                              hipStream_t stream)
{
    const float* P     = (const float*)d_in[0];   // params (B,C,T) fp32
    const int*   seq   = (const int*)  d_in[1];   // (B,S) int32
    // d_in[2] = lengths (unused by the reference computation)
    const int*   blank = (const int*)  d_in[3];   // scalar int

    // ws layout (bf16 rows): Wa | Wb (34.1 MB each) | W4a | W4b | Lq | Eb
    ushort* Wa  = (ushort*)d_ws;
    ushort* Wb  = Wa  + (size_t)BB*TT*LPADH;
    ushort* W4a = Wb  + (size_t)BB*TT*LPADH;      // BB*TT ushorts (128 KB)
    ushort* W4b = W4a + (size_t)BB*TT;
    double* Lq  = (double*)(W4b + (size_t)BB*TT); // 8192 doubles
    int*    Eb  = (int*)(Lq + (size_t)BB*64);     // 8192 ints
    (void)ws_size; (void)in_sizes; (void)n_in; (void)out_size;

    ctc_scan<<<2*BB, 128, 0, stream>>>(P, seq, blank, Wa, Wb, W4a, W4b, Eb);
    ctc_combine<<<dim3(BB, 64), 64, 0, stream>>>(Wa, Wb, W4a, W4b, Eb, seq, Lq);
    ctc_final<<<1, 256, 0, stream>>>(Lq, (float*)d_out);
}

// Round 18
// 58.347 us; speedup vs baseline: 1.1171x; 1.0644x over previous
//
#include <hip/hip_runtime.h>
#include <math.h>

// CTC loss (per-step-normalized fwd/bwd), B=128, C=512, T=512, S=128, L=257.
// Round-18: r17 + counted-barrier fix. __syncthreads() compiles to
// s_waitcnt vmcnt(0) lgkmcnt(0) + s_barrier (guide m97), so the off-wave's
// scattered gathers (~1500-2000cy return) DRAIN on the critical path every
// slot -- this reconciles the observed 3300cy/slot vs ~1500 composed issue.
// Fix: lgkmcnt(0) (LDS handoff only) + raw s_barrier; gathers' completion is
// handled by the compiler's counted vmcnt before first use, one slot later
// (HK T4: never drain vmcnt in the loop). Plus pk_bf16 via one v_perm_b32.
// Combine/final: r15 verbatim. Identity (r4-r17): lh_t = sigma*D/(S*R).
// bf16 rows; fp64 block accumulation; clamps -> no NaN possible.

#define BB 128
#define CC 512
#define TT 512
#define SS 128
#define LL 257
#define LPADH 260   // bf16 (ushort) elements per row

typedef unsigned int  uint;
typedef unsigned short ushort;

// ---- fp32 DPP helpers (gfx9 controls; validated on gfx950 rounds 3-17) ----
template<int CTRL>
__device__ __forceinline__ float dpp0_f32(float x){
    int v = __builtin_bit_cast(int, x);
    int r = __builtin_amdgcn_update_dpp(0, v, CTRL, 0xF, 0xF, true);
    return __builtin_bit_cast(float, r);
}
__device__ __forceinline__ float shfl_up1_f32(float x){ return dpp0_f32<0x138>(x); }
__device__ __forceinline__ float red8f(float x){
    x += dpp0_f32<0x111>(x);
    x += dpp0_f32<0x112>(x);
    x += dpp0_f32<0x114>(x);
    return x;
}
__device__ __forceinline__ float tail3f(float x){
    x += dpp0_f32<0x118>(x);
    x += dpp0_f32<0x142>(x);
    x += dpp0_f32<0x143>(x);
    return x;
}
__device__ __forceinline__ float full64f(float x){ return tail3f(red8f(x)); }
__device__ __forceinline__ float readlane63_f32(float x){
    int v = __builtin_bit_cast(int, x);
    return __builtin_bit_cast(float, __builtin_amdgcn_readlane(v, 63));
}
__device__ __forceinline__ float pow2if(int e){
    return __builtin_bit_cast(float, (127 + e) << 23);
}
// pack two fp32 -> bf16 pair via one v_perm_b32 (truncation, same bits as
// (hi&0xFFFF0000)|(lo>>16): dest bytes {hi3,hi2,lo3,lo2} = sel 0x07060302)
__device__ __forceinline__ uint pk_bf16(float lo, float hi){
    return __builtin_amdgcn_perm(__builtin_bit_cast(uint, hi),
                                 __builtin_bit_cast(uint, lo), 0x07060302u);
}
__device__ __forceinline__ float up_lo(uint u){ return __builtin_bit_cast(float, u << 16); }
__device__ __forceinline__ float up_hi(uint u){ return __builtin_bit_cast(float, u & 0xFFFF0000u); }
__device__ __forceinline__ float up_us(ushort u){ return __builtin_bit_cast(float, ((uint)u) << 16); }
template<int CTRL>
__device__ __forceinline__ double dpp0_f64(double x){
    int2 v = __builtin_bit_cast(int2, x);
    int2 r;
    r.x = __builtin_amdgcn_update_dpp(0, v.x, CTRL, 0xF, 0xF, true);
    r.y = __builtin_amdgcn_update_dpp(0, v.y, CTRL, 0xF, 0xF, true);
    return __builtin_bit_cast(double, r);
}
__device__ __forceinline__ double full64d(double x){
    x += dpp0_f64<0x111>(x); x += dpp0_f64<0x112>(x); x += dpp0_f64<0x114>(x);
    x += dpp0_f64<0x118>(x); x += dpp0_f64<0x142>(x); x += dpp0_f64<0x143>(x);
    return x;
}

// LDS-only barrier: order the state handoff without draining vmem (the
// __syncthreads drain put gather-return latency on the critical path).
__device__ __forceinline__ void lds_barrier(){
    asm volatile("s_waitcnt lgkmcnt(0)" ::: "memory");
    __builtin_amdgcn_s_barrier();
    __builtin_amdgcn_sched_barrier(0);
    asm volatile("" ::: "memory");
}

// ============ 2-wave producer/consumer scan; 16-step slots; float4 gathers ============
template<bool REV>
__device__ __forceinline__ void scan_body(
    int b, int wv, int l, const float* __restrict__ P,
    const int* __restrict__ seqg, int blank,
    ushort* __restrict__ W, ushort* __restrict__ W4, int* __restrict__ Eb)
{
    __shared__ float4 st4[64];
    __shared__ float  st1[64];
    __shared__ float  scSh[1];

    const bool is63 = (l == 63);
    const float* Pb = P + (size_t)b * (CC*TT);
    const int* sq = seqg + b*SS;

    int r1, r3; float m1, m3;
    if (!REV) {
        r1 = sq[2*l]; r3 = sq[2*l+1];
        int ip = (l==0) ? 0 : (2*l-1);
        m1 = (l==0) ? 1.f : ((r1 != sq[ip]) ? 1.f : 0.f);
        m3 = (r3 != r1) ? 1.f : 0.f;
    } else {
        r1 = sq[SS-1-2*l]; r3 = sq[SS-2-2*l];
        int ip = (l==0) ? 0 : (SS-2*l);
        m1 = (l==0) ? 1.f : ((r1 != sq[ip]) ? 1.f : 0.f);
        m3 = (r3 != r1) ? 1.f : 0.f;
    }
    const float* pBp = Pb + (size_t)blank*TT;
    const float* p1p = Pb + (size_t)r1*TT;
    const float* p3p = Pb + (size_t)r3*TT;
    int* EbB = Eb + b*64;

    const int tm0=(4*l+769)>>1, tm1=(4*l+770)>>1, tm2=(4*l+771)>>1, tm3=(4*l+772)>>1;

    float a0=0.f,a1=0.f,a2=0.f,a3=0.f,a4=0.f;
    float scNext = 1.f, Sfull = 0.f;
    const float u0i = (l==0) ? 1.f : 0.f;
    float4 qB[4], q1[4], q3[4];           // 16 columns (one slot), float4 chunks
    uint sbLo[16], sbHi[16]; float s4f[16];

#define COMP4(v,c) ((c)==0?(v).x:((c)==1?(v).y:((c)==2?(v).z:(v).w)))

// load the 4 float4 column-chunks (per row) covering slot ss (steps 16ss..16ss+15)
#define LOADPG2(ss)                                                         \
  { const int base_ = REV ? (TT - 16*(ss) - 4) : (16*(ss));                 \
    _Pragma("unroll")                                                       \
    for (int k=0;k<4;++k){                                                  \
      int c_ = REV ? (base_ - 4*k) : (base_ + 4*k);                         \
      qB[k] = *reinterpret_cast<const float4*>(pBp + c_);                   \
      q1[k] = *reinterpret_cast<const float4*>(p1p + c_);                   \
      q3[k] = *reinterpret_cast<const float4*>(p3p + c_);                   \
    } }

#define STEP16(ss, j, FIRSTF, MASKF)                                        \
  {                                                                         \
    const int i = 16*(ss) + (j);                                            \
    float u0,u1,u2,u3,u4;                                                   \
    if (FIRSTF) { u0=u0i; u1=u0i; u2=0.f; u3=0.f; u4=0.f; }                 \
    else {                                                                  \
      float e3u = shfl_up1_f32(a3);                                         \
      u0 = a0 + e3u; u1 = (a1+a0) + m1*e3u; u2 = a2+a1;                     \
      u3 = (a3+a2) + m3*a1; u4 = a4+a3;                                     \
      if (MASKF) {                                                          \
        if (i >= tm0) u0 = 0.f;                                             \
        if (i >= tm1) u1 = 0.f;                                             \
        if (i >= tm2) u2 = 0.f;                                             \
        if (i >= tm3) u3 = 0.f;                                             \
      }                                                                     \
    }                                                                       \
    constexpr int ch_ = (j) >> 2;                                           \
    constexpr int cm_ = REV ? ((3-(j)) & 3) : ((j) & 3);                    \
    float pB = COMP4(qB[ch_], cm_);                                         \
    float pq = COMP4(q1[ch_], cm_);                                         \
    float pr = COMP4(q3[ch_], cm_);                                         \
    if (((j)&7)==0) { pB*=scNext; pq*=scNext; pr*=scNext; }                 \
    float n0=u0*pB, n1=u1*pq, n2=u2*pB, n3=u3*pr, n4=u4*pB;                 \
    sbLo[j]=pk_bf16(n0,n1); sbHi[j]=pk_bf16(n2,n3); s4f[j]=n4;              \
    if (((j)&7)==5) {                                                       \
      float part=(n0+n1)+(n2+n3); if (is63) part+=n4;                       \
      Sfull = full64f(part);                                                \
    }                                                                       \
    if (((j)&7)==7) {                                                       \
      float Su = readlane63_f32(Sfull);                                     \
      int ex = (__builtin_bit_cast(int, Su) >> 23) & 0xFF;                  \
      int e = (ex==0) ? 0 : (ex-127);                                       \
      e = e < -120 ? -120 : (e > 120 ? 120 : e);                            \
      scNext = pow2if(-e);                                                  \
      const int g_ = i >> 3;                                                \
      if (REV && l==0 && g_+1 < 64) EbB[g_+1] = e;                          \
    }                                                                       \
    a0=n0; a1=n1; a2=n2; a3=n3; a4=n4;                                      \
  }

#define RG2(ss, FIRSTF, MASKF)                                              \
    STEP16(ss,0,FIRSTF,MASKF) STEP16(ss,1,false,MASKF)                      \
    STEP16(ss,2,false,MASKF)  STEP16(ss,3,false,MASKF)                      \
    STEP16(ss,4,false,MASKF)  STEP16(ss,5,false,MASKF)                      \
    STEP16(ss,6,false,MASKF)  STEP16(ss,7,false,MASKF)                      \
    STEP16(ss,8,false,MASKF)  STEP16(ss,9,false,MASKF)                      \
    STEP16(ss,10,false,MASKF) STEP16(ss,11,false,MASKF)                     \
    STEP16(ss,12,false,MASKF) STEP16(ss,13,false,MASKF)                     \
    STEP16(ss,14,false,MASKF) STEP16(ss,15,false,MASKF)

#define STOREROWS2(ss)                                                      \
  {                                                                         \
    ushort* Ww = W + ((size_t)b*TT + (size_t)(ss)*16) * LPADH;              \
    _Pragma("unroll")                                                       \
    for (int j=0;j<16;++j)                                                  \
      *reinterpret_cast<uint2*>(Ww + (size_t)j*LPADH + 4*l)                 \
          = make_uint2(sbLo[j], sbHi[j]);                                   \
    if (is63) {                                                             \
      uint4 pk0, pk1;                                                       \
      pk0.x = pk_bf16(s4f[0], s4f[1]);   pk0.y = pk_bf16(s4f[2], s4f[3]);   \
      pk0.z = pk_bf16(s4f[4], s4f[5]);   pk0.w = pk_bf16(s4f[6], s4f[7]);   \
      pk1.x = pk_bf16(s4f[8], s4f[9]);   pk1.y = pk_bf16(s4f[10], s4f[11]); \
      pk1.z = pk_bf16(s4f[12], s4f[13]); pk1.w = pk_bf16(s4f[14], s4f[15]); \
      ushort* w4p = W4 + (size_t)b*TT + (size_t)(ss)*16;                    \
      *reinterpret_cast<uint4*>(w4p)     = pk0;                             \
      *reinterpret_cast<uint4*>(w4p + 8) = pk1;                             \
    }                                                                       \
  }

    LOADPG2(wv)                      // preload my first owned slot's columns

    for (int s = 0; s < 32; ++s) {
        if ((s & 1) == wv) {
            // ---- owner: recursion core only ----
            if (s > 0) {
                float4 v = st4[l];
                a0 = v.x; a1 = v.y; a2 = v.z; a3 = v.w;
                a4 = st1[l];
                scNext = scSh[0];
            }
            if (s == 0)      { RG2(0, true,  false) }
            else if (s < 24) { RG2(s, false, false) }
            else             { RG2(s, false, true ) }
            st4[l] = make_float4(a0, a1, a2, a3);
            st1[l] = a4;
            if (l == 0) scSh[0] = scNext;
        } else {
            // ---- off-phase: store my previous slot, gather my next ----
            if (s >= 1) STOREROWS2(s-1)
            if (s >= 1 && s < 31) LOADPG2(s+1)
        }
        lds_barrier();   // LDS-handoff order only; vmem stays in flight
    }
    if (wv == 1) STOREROWS2(31)      // last slot's rows

#undef STEP16
#undef RG2
#undef STOREROWS2
#undef LOADPG2
#undef COMP4
}

__global__ __launch_bounds__(128, 1)
void ctc_scan(const float* __restrict__ P, const int* __restrict__ seqg,
              const int* __restrict__ blankp, ushort* __restrict__ Wa,
              ushort* __restrict__ Wb, ushort* __restrict__ W4a,
              ushort* __restrict__ W4b, int* __restrict__ Eb)
{
    const int bx = blockIdx.x;
    const int wv = threadIdx.x >> 6, l = threadIdx.x & 63;
    const int blank = blankp[0];
    if (bx < BB) scan_body<false>(bx,      wv, l, P, seqg, blank, Wa, W4a, Eb);
    else         scan_body<true >(bx - BB, wv, l, P, seqg, blank, Wb, W4b, Eb);
}

// ============== combine: r15 verbatim (exponent/mantissa logs) ==============
__global__ __launch_bounds__(64)
void ctc_combine(const ushort* __restrict__ Wa, const ushort* __restrict__ Wb,
                 const ushort* __restrict__ W4a, const ushort* __restrict__ W4b,
                 const int* __restrict__ Eb, const int* __restrict__ seqg,
                 double* __restrict__ Lq)
{
    const int b = blockIdx.x, q = blockIdx.y, l = threadIdx.x;
    const bool is63 = (l == 63);
    const int* sq = seqg + b*SS;
    const int r1 = sq[SS-1-2*l], r3 = sq[SS-2-2*l];
    const int ip = (l==0) ? 0 : (SS-2*l);
    const float m1 = (l==0) ? 1.f : ((r1 != sq[ip]) ? 1.f : 0.f);
    const float m3 = (r3 != r1) ? 1.f : 0.f;
    const int tm0=(4*l+769)>>1, tm1=(4*l+770)>>1, tm2=(4*l+771)>>1, tm3=(4*l+772)>>1;

    const ushort* WaB = Wa + (size_t)b*TT*LPADH;
    const ushort* WbB = Wb + (size_t)b*TT*LPADH;
    const ushort* W4aB = W4a + (size_t)b*TT;
    const ushort* W4bB = W4b + (size_t)b*TT;
    const int t0 = q*8;

    float Rcur;
    {
        const ushort* rw = WbB + (size_t)(TT-1-t0)*LPADH;
        uint2 xu = *reinterpret_cast<const uint2*>(rw + 4*l);
        float rnp = (up_lo(xu.x)+up_hi(xu.x))+(up_lo(xu.y)+up_hi(xu.y));
        if (is63) rnp += up_us(W4bB[TT-1-t0]);
        Rcur = full64f(rnp);
    }

    float PmN = 1.f, PmD = 1.f;
    int   Ei  = 0;

    #pragma unroll
    for (int k=0; k<8; ++k) {
        const int t = t0 + k;
        const int i = TT-1-t;
        const ushort* arow = WaB + (size_t)t*LPADH;
        uint2 au = *reinterpret_cast<const uint2*>(arow + (252 - 4*l));
        float av0 = up_lo(au.x), av1 = up_hi(au.x);
        float av2 = up_lo(au.y), av3 = up_hi(au.y);
        float a256 = up_us(W4aB[t]);
        float ar4 = shfl_up1_f32(av0);
        if (l == 0) ar4 = a256;

        float u0,u1,u2,u3,u4, rnext = 0.f;
        if (i > 0) {
            const ushort* rw = WbB + (size_t)(i-1)*LPADH;
            uint2 bu = *reinterpret_cast<const uint2*>(rw + 4*l);
            float bv0 = up_lo(bu.x), bv1 = up_hi(bu.x);
            float bv2 = up_lo(bu.y), bv3 = up_hi(bu.y);
            float b4 = up_us(W4bB[i-1]);
            float e3u = shfl_up1_f32(bv3);
            u0 = bv0 + e3u;
            u1 = (bv1 + bv0) + m1*e3u;
            u2 = bv2 + bv1;
            u3 = (bv3 + bv2) + m3*bv1;
            u4 = b4 + bv3;
            if (i >= TT - SS) {
                if (i >= tm0) u0 = 0.f;
                if (i >= tm1) u1 = 0.f;
                if (i >= tm2) u2 = 0.f;
                if (i >= tm3) u3 = 0.f;
            }
            rnext = (bv0+bv1)+(bv2+bv3);
            if (is63) rnext += b4;
        } else {
            u0 = (l==0)?1.f:0.f; u1 = u0; u2=0.f; u3=0.f; u4=0.f;
        }
        float trp = ar4*u0 + av3*u1 + av2*u2 + av1*u3;
        if (is63) trp += av0*u4;
        float sap = (av1 + av2) + (av3 + ar4);
        if (is63) sap += av0;

        float D  = full64f(trp);
        float S  = full64f(sap);
        float Rn = full64f(rnext);
        if (is63) {
            float dd = fmaxf(D, 1e-37f);
            uint bn = __builtin_bit_cast(uint, dd);
            Ei += (int)((bn >> 23) & 0xFFu) - 127;
            PmN *= __builtin_bit_cast(float, (bn & 0x807FFFFFu) | (127u<<23));
            float sr = fmaxf(S * Rcur, 1e-37f);
            uint bd = __builtin_bit_cast(uint, sr);
            Ei -= (int)((bd >> 23) & 0xFFu) - 127;
            PmD *= __builtin_bit_cast(float, (bd & 0x807FFFFFu) | (127u<<23));
            if (i > 0 && (i & 7) == 0) Ei -= Eb[b*64 + (i>>3)];
        }
        Rcur = Rn;
    }
    if (is63)
        Lq[b*64 + q] = log((double)PmN / (double)PmD) + (double)Ei * M_LN2;
}

__global__ __launch_bounds__(256)
void ctc_final(const double* __restrict__ Lq, float* __restrict__ out)
{
    const int t = threadIdx.x;
    double v = 0.0;
    #pragma unroll
    for (int k=0;k<32;++k) v += Lq[t + 256*k];
    double s = full64d(v);
    __shared__ double w[4];
    if ((t & 63) == 63) w[t>>6] = s;
    __syncthreads();
    if (t == 0) out[0] = (float)(-(w[0]+w[1]+w[2]+w[3]));
}

extern "C" void kernel_launch(void* const* d_in, const int* in_sizes, int n_in,
                              void* d_out, int out_size, void* d_ws, size_t ws_size,
                              hipStream_t stream)
{
    const float* P     = (const float*)d_in[0];   // params (B,C,T) fp32
    const int*   seq   = (const int*)  d_in[1];   // (B,S) int32
    // d_in[2] = lengths (unused by the reference computation)
    const int*   blank = (const int*)  d_in[3];   // scalar int

    // ws layout (bf16 rows): Wa | Wb (34.1 MB each) | W4a | W4b | Lq | Eb
    ushort* Wa  = (ushort*)d_ws;
    ushort* Wb  = Wa  + (size_t)BB*TT*LPADH;
    ushort* W4a = Wb  + (size_t)BB*TT*LPADH;      // BB*TT ushorts (128 KB)
    ushort* W4b = W4a + (size_t)BB*TT;
    double* Lq  = (double*)(W4b + (size_t)BB*TT); // 8192 doubles
    int*    Eb  = (int*)(Lq + (size_t)BB*64);     // 8192 ints
    (void)ws_size; (void)in_sizes; (void)n_in; (void)out_size;

    ctc_scan<<<2*BB, 128, 0, stream>>>(P, seq, blank, Wa, Wb, W4a, W4b, Eb);
    ctc_combine<<<dim3(BB, 64), 64, 0, stream>>>(Wa, Wb, W4a, W4b, Eb, seq, Lq);
    ctc_final<<<1, 256, 0, stream>>>(Lq, (float*)d_out);
}